// Round 10
// baseline (100.999 us; speedup 1.0000x reference)
//
#include <hip/hip_runtime.h>
#include <stdint.h>

// ---------------- fixed problem geometry (validated by out_size) -------------
#define NBATCH   8
#define TT       8
#define NPTS     6890
#define KCLS     7
#define CCH      128
#define BSAMP    64            // NBATCH*TT
#define NOUT     1722          // n = NPTS/4
#define DSUM     512
#define PCADIM   64
#define V3       23106         // 7702*3
#define EPSBN    1e-5f

#define NW       108           // mask words per sample (64 pts each)
#define PCH      512           // points per gather chunk (= 8 mask words)
#define NCHK     14            // ceil(NPTS/512); last chunk = 234 pts (guarded path)
#define CHN      32            // channels per gather block
#define CHB      4             // channel blocks
#define LDSR     516           // padded row length (floats); 516*4 % 16 == 0
#define CPG      7             // chunks per gather block
#define NGRP     2             // 2 groups * 7 chunks = 14 chunks
#define K4B      91            // tpose blocks (first in K2 grid)
#define NGATHER  (BSAMP * CHB * NGRP)   // 512 -> exactly 2/CU resident

// output layout (flat f32)
#define OFF_GV     0
#define OFF_GF     (BSAMP * NOUT * 3)                 // 330624
#define OFF_COEFF  (OFF_GF + BSAMP * NOUT * CCH)      // 14437248
#define OFF_TPOSE  (OFF_COEFF + NBATCH * PCADIM)      // 14437760

// async HBM -> LDS, 16B/lane, LDS dst wave-uniform (lane*16 auto-offset)
__device__ __forceinline__ void gl_lds16(const float* g, float* l) {
    __builtin_amdgcn_global_load_lds(
        (const __attribute__((address_space(1))) uint32_t*)g,
        (__attribute__((address_space(3))) uint32_t*)l,
        16, 0, 0);
}

// ------- kernel 1: {argmax mask (1728 blocks)} || {MLP (8 blocks)} -----------
__global__ __launch_bounds__(256) void k1_mask_mlp(
    const float* __restrict__ logits,            // [BSAMP, NPTS, KCLS]
    const int*   __restrict__ d_label,
    unsigned long long* __restrict__ ws_mask,    // [BSAMP, NW]
    const float* __restrict__ gsum,
    const float* __restrict__ W1, const float* __restrict__ b1,
    const float* __restrict__ g1, const float* __restrict__ be1,
    const float* __restrict__ rm1, const float* __restrict__ rv1,
    const float* __restrict__ W2, const float* __restrict__ b2,
    const float* __restrict__ g2, const float* __restrict__ be2,
    const float* __restrict__ rm2, const float* __restrict__ rv2,
    const float* __restrict__ W3, const float* __restrict__ b3,
    float* __restrict__ coeff_out, float* __restrict__ coeff_ws)
{
    const int tid = threadIdx.x;

    if (blockIdx.x < BSAMP * 27) {
        // ---------------- mask part ----------------
        const int b     = blockIdx.x / 27;
        const int chunk = blockIdx.x % 27;
        const int i     = chunk * 256 + tid;
        const int label = d_label[0];

        bool sel = false;
        if (i < NPTS) {
            const float* p = logits + ((size_t)b * NPTS + i) * KCLS;
            float best = p[0]; int bi = 0;
            #pragma unroll
            for (int k = 1; k < KCLS; ++k) {
                float v = p[k];
                if (v > best) { best = v; bi = k; }
            }
            sel = (bi == label);
        }
        const unsigned long long m = __ballot(sel);
        if ((tid & 63) == 0) {
            const int w = chunk * 4 + (tid >> 6);
            if (w < NW) ws_mask[b * NW + w] = m;
        }
    } else {
        // ---------------- MLP part (8 blocks) ----------------
        const int s    = blockIdx.x - BSAMP * 27;
        const int lane = tid & 63;
        const int wv   = tid >> 6;

        __shared__ float gs[DSUM];
        __shared__ float h1[128];
        __shared__ float h2[64];

        for (int d = tid; d < DSUM; d += 256) {
            const float* p = gsum + ((size_t)s * TT) * DSUM + d;
            float m = p[0];
            #pragma unroll
            for (int t = 1; t < TT; ++t) m = fmaxf(m, p[(size_t)t * DSUM]);
            gs[d] = m;
        }
        __syncthreads();

        for (int r = 0; r < 32; r += 2) {
            const int j0 = wv * 32 + r, j1 = j0 + 1;
            const float* w0 = W1 + (size_t)j0 * DSUM;
            const float* w1 = W1 + (size_t)j1 * DSUM;
            float pa = 0.f, pb = 0.f;
            #pragma unroll
            for (int d = lane; d < DSUM; d += 64) {
                const float gd = gs[d];
                pa = fmaf(w0[d], gd, pa);
                pb = fmaf(w1[d], gd, pb);
            }
            #pragma unroll
            for (int off = 32; off; off >>= 1) {
                pa += __shfl_xor(pa, off);
                pb += __shfl_xor(pb, off);
            }
            if (lane == 0) {
                pa += b1[j0];
                pa = (pa - rm1[j0]) * rsqrtf(rv1[j0] + EPSBN) * g1[j0] + be1[j0];
                h1[j0] = fmaxf(pa, 0.f);
                pb += b1[j1];
                pb = (pb - rm1[j1]) * rsqrtf(rv1[j1] + EPSBN) * g1[j1] + be1[j1];
                h1[j1] = fmaxf(pb, 0.f);
            }
        }
        __syncthreads();

        for (int r = 0; r < 16; ++r) {
            const int jj = wv * 16 + r;
            const float* w = W2 + (size_t)jj * 128;
            float p = w[lane] * h1[lane] + w[lane + 64] * h1[lane + 64];
            #pragma unroll
            for (int off = 32; off; off >>= 1) p += __shfl_xor(p, off);
            if (lane == 0) {
                p += b2[jj];
                p = (p - rm2[jj]) * rsqrtf(rv2[jj] + EPSBN) * g2[jj] + be2[jj];
                h2[jj] = fmaxf(p, 0.f);
            }
        }
        __syncthreads();

        for (int r = 0; r < 16; ++r) {
            const int jj = wv * 16 + r;
            float p = W3[(size_t)jj * 64 + lane] * h2[lane];
            #pragma unroll
            for (int off = 32; off; off >>= 1) p += __shfl_xor(p, off);
            if (lane == 0) {
                p += b3[jj];
                coeff_out[s * PCADIM + jj] = p;
                coeff_ws[s * PCADIM + jj]  = p;
            }
        }
    }
}

// ------- kernel 2: {tpose (91)} || {DMA gather + gv + tails (512)} -----------
// Gather block = (b, cb of 32 ch, g of 7 chunks of 512 pts).
// Reads: global_load_lds 16B/lane -> 2x1KB back-to-back per channel row per
// chunk (2KB sequential per stream-visit, zero VGPR staging).
__global__ __launch_bounds__(256, 2) void k2_all(
    const float* __restrict__ feature,           // [BSAMP, CCH, NPTS]
    const unsigned long long* __restrict__ ws_mask,
    const float* __restrict__ x,                 // [BSAMP, NPTS, 3]
    float* __restrict__ gv,                      // [BSAMP, NOUT, 3]
    float* __restrict__ gf,                      // [BSAMP, NOUT, CCH]
    const float* __restrict__ coeff_ws,
    const float* __restrict__ comp,
    const float* __restrict__ mean_,
    const float* __restrict__ scale_,
    float* __restrict__ tpose)
{
    __shared__ float lds[CHN * LDSR];            // 66048 B data buffer
    __shared__ unsigned long long smask[NW];
    __shared__ int  swc[NW];                     // popcount -> exclusive prefix
    __shared__ int  sel_list[8 * 64];            // packed (p | pos<<9) per word
    __shared__ int  s_ns[8];
    __shared__ int  s_cnt;

    const int tid = threadIdx.x;

    if (blockIdx.x < K4B) {
        // ---------------- tpose part ----------------
        float* sc = lds;
        for (int o = tid; o < NBATCH * PCADIM; o += 256) sc[o] = coeff_ws[o];
        __syncthreads();

        const int v = blockIdx.x * 256 + tid;
        if (v >= V3) return;

        float acc[NBATCH];
        #pragma unroll
        for (int s = 0; s < NBATCH; ++s) acc[s] = 0.f;
        for (int k = 0; k < PCADIM; ++k) {
            const float pv = comp[(size_t)k * V3 + v];
            #pragma unroll
            for (int s = 0; s < NBATCH; ++s)
                acc[s] = fmaf(sc[s * PCADIM + k], pv, acc[s]);
        }
        const float mn = mean_[v], scl = scale_[v];
        #pragma unroll
        for (int s = 0; s < NBATCH; ++s)
            tpose[(size_t)s * V3 + v] = (acc[s] + mn) * scl;
        return;
    }

    // ---------------- gather part ----------------
    const int gb  = blockIdx.x - K4B;
    const int b   = gb / (CHB * NGRP);
    const int rem = gb % (CHB * NGRP);
    const int cb  = rem / NGRP;                  // 0..3
    const int g   = rem % NGRP;                  // 0..1
    const int idx = cb * NGRP + g;               // 0..7 (per-sample share id)

    const int lane = tid & 63;
    const int wv   = tid >> 6;                   // wave -> rows wv*8..wv*8+7
    const float* fbase = feature + ((size_t)b * CCH + cb * CHN) * NPTS;

    // prologue: mask + exclusive prefix in LDS
    if (tid < NW) smask[tid] = ws_mask[b * NW + tid];
    __syncthreads();
    if (tid < NW) swc[tid] = __popcll(smask[tid]);
    __syncthreads();
    if (tid == 0) {
        int run = 0;
        for (int w = 0; w < NW; ++w) { int t = swc[w]; swc[w] = run; run += t; }
        s_cnt = run < NOUT ? run : NOUT;
    }
    __syncthreads();

    // gv share: points [idx*862, +862) of this sample
    {
        const int i0s = idx * 862;
        const int i1s = min(i0s + 862, NPTS);
        const float* xb = x + (size_t)b * NPTS * 3;
        for (int i = i0s + tid; i < i1s; i += 256) {
            const int w = i >> 6, lb6 = i & 63;
            const unsigned long long m = smask[w];
            if ((m >> lb6) & 1ull) {
                const int pos = swc[w] + __popcll(m & ((1ull << lb6) - 1ull));
                if (pos < NOUT) {
                    const size_t go = ((size_t)b * NOUT + pos) * 3;
                    gv[go + 0] = xb[(size_t)i * 3 + 0];
                    gv[go + 1] = xb[(size_t)i * 3 + 1];
                    gv[go + 2] = xb[(size_t)i * 3 + 2];
                }
            }
        }
    }
    // gv + gf tail-zero shares (8 shares per sample)
    {
        const int cnt  = s_cnt;
        const int tail = NOUT - cnt;
        if (tail > 0) {
            const int share = (tail + 7) / 8;
            const int r0    = cnt + idx * share;
            const int r1    = min(r0 + share, NOUT);
            if (r1 > r0) {
                for (int j = r0 + tid; j < r1; j += 256) {
                    float* gp = gv + ((size_t)b * NOUT + j) * 3;
                    gp[0] = 0.f; gp[1] = 0.f; gp[2] = 0.f;
                }
                float4* base4 = (float4*)(gf + ((size_t)b * NOUT + r0) * CCH);
                const int total = (r1 - r0) * 32;
                for (int f = tid; f < total; f += 256)
                    base4[f] = make_float4(0.f, 0.f, 0.f, 0.f);
            }
        }
    }

    // chunk loop: single-buffered DMA, 2 barriers per chunk
    #pragma unroll 1
    for (int c = 0; c < CPG; ++c) {
        const int chunk = g * CPG + c;
        const int i0    = chunk * PCH;

        __syncthreads();                         // bar_a: LDS + sel arrays free

        if (chunk != NCHK - 1) {
            // full chunk: 2KB DMA per row (2 x 1KB global_load_lds)
            #pragma unroll
            for (int it = 0; it < 8; ++it) {
                const int r = wv * 8 + it;
                const float* src = fbase + (size_t)r * NPTS + i0;
                float* dst = &lds[r * LDSR];
                gl_lds16(src + lane * 4,       dst);
                gl_lds16(src + 256 + lane * 4, dst + 256);
            }
        } else {
            // tail chunk (234 pts): guarded scalar loads, no overread
            const int il = NPTS - i0;
            #pragma unroll
            for (int it = 0; it < 8; ++it) {
                const int r = wv * 8 + it;
                const float* src = fbase + (size_t)r * NPTS + i0;
                for (int off = lane; off < il; off += 64)
                    lds[r * LDSR + off] = src[off];
            }
        }

        // selection for this chunk's 8 words (computed under load flight)
        #pragma unroll
        for (int j = 0; j < 2; ++j) {
            const int wk   = 2 * wv + j;         // 0..7
            const int word = chunk * 8 + wk;
            unsigned long long m = 0; int base = 0;
            if (word < NW) { m = smask[word]; base = swc[word]; }
            const int sel = (int)((m >> lane) & 1ull);
            const int pos = base + __popcll(m & ((1ull << lane) - 1ull));
            const bool ok = sel && pos < NOUT;
            const unsigned long long mm = __ballot(ok);
            const int before = __popcll(mm & ((1ull << lane) - 1ull));
            if (ok) sel_list[wk * 64 + before] = (wk * 64 + lane) | (pos << 9);
            if (lane == 0) s_ns[wk] = __popcll(mm);
        }

        __syncthreads();                         // bar_b: DMA + sel complete

        // phase B: wave wv drains words {2wv, 2wv+1}; 128B row-writes,
        // 2 points per wave-op, 2-deep software pipeline
        {
            const int half = lane >> 5;
            const int ch   = lane & 31;
            float* gfb = gf + (size_t)b * NOUT * CCH + cb * CHN + ch;
            #pragma unroll
            for (int j = 0; j < 2; ++j) {
                const int wk = 2 * wv + j;
                const int ns = s_ns[wk];
                int s = half;
                if (s < ns) {
                    int e = sel_list[wk * 64 + s];
                    int p = e & 511, pos = e >> 9;
                    float v = lds[ch * LDSR + p];
                    for (s += 2; s < ns; s += 2) {
                        const int e2 = sel_list[wk * 64 + s];
                        const int p2 = e2 & 511, pos2 = e2 >> 9;
                        const float v2 = lds[ch * LDSR + p2];
                        gfb[(size_t)pos * CCH] = v;
                        v = v2; pos = pos2;
                    }
                    gfb[(size_t)pos * CCH] = v;
                }
            }
        }
    }
}

// ---------------- launcher ---------------------------------------------------
extern "C" void kernel_launch(void* const* d_in, const int* in_sizes, int n_in,
                              void* d_out, int out_size, void* d_ws, size_t ws_size,
                              hipStream_t stream) {
    const float* x      = (const float*)d_in[0];
    const float* logits = (const float*)d_in[1];
    const float* feat   = (const float*)d_in[2];
    const float* gsum   = (const float*)d_in[3];
    const float* W1  = (const float*)d_in[4];
    const float* b1  = (const float*)d_in[5];
    const float* g1  = (const float*)d_in[6];
    const float* be1 = (const float*)d_in[7];
    const float* rm1 = (const float*)d_in[8];
    const float* rv1 = (const float*)d_in[9];
    const float* W2  = (const float*)d_in[10];
    const float* b2  = (const float*)d_in[11];
    const float* g2  = (const float*)d_in[12];
    const float* be2 = (const float*)d_in[13];
    const float* rm2 = (const float*)d_in[14];
    const float* rv2 = (const float*)d_in[15];
    const float* W3  = (const float*)d_in[16];
    const float* b3  = (const float*)d_in[17];
    const float* comp  = (const float*)d_in[18];
    const float* mean_ = (const float*)d_in[19];
    const float* scale_= (const float*)d_in[20];
    const int* d_label = (const int*)d_in[21];

    float* out   = (float*)d_out;
    float* gv    = out + OFF_GV;
    float* gf    = out + OFF_GF;
    float* coeff = out + OFF_COEFF;
    float* tpose = out + OFF_TPOSE;

    unsigned long long* ws_mask = (unsigned long long*)d_ws;      // 64*108 u64
    float* coeff_ws = (float*)(ws_mask + BSAMP * NW);             // 512 f32

    k1_mask_mlp<<<BSAMP * 27 + NBATCH, 256, 0, stream>>>(
        logits, d_label, ws_mask, gsum, W1, b1, g1, be1, rm1, rv1,
        W2, b2, g2, be2, rm2, rv2, W3, b3, coeff, coeff_ws);

    k2_all<<<K4B + NGATHER, 256, 0, stream>>>(
        feat, ws_mask, x, gv, gf, coeff_ws, comp, mean_, scale_, tpose);
}